// Round 25
// baseline (86.626 us; speedup 1.0000x reference)
//
#include <hip/hip_runtime.h>
#include <hip/hip_fp16.h>

#define S_SIGMA 8
#define NBINS   16
#define HDIM    1024
#define WDIM    1024
#define GH      129   // (1024-1)/8 + 2
#define GW      129
#define GZ      17    // NBINS + 1
#define CELLS   (GH*GW*GZ)   // 282897 cells per image
#define ROWSZ   (GW*GZ)      // 2193 cells per grid row
#define EPSV    1e-8f
// packed bin: count in bits 25..31 (max 81 < 128), val*4096 in bits 0..24
#define PKONE   (1u << 25)
#define PKMASK  0x1FFFFFFu
#define PKSCL   4096.0f
#define PKINV   (1.0f/4096.0f)

// Grids stored as half2 (val, wt): 4 B/cell (r24 win). f32 arithmetic/LDS.

// Bijective XCD swizzle (m204): contiguous work chunk per XCD.
__device__ __forceinline__ int xcd_swizzle(int orig, int nwg) {
    int q = nwg >> 3, r = nwg & 7;
    int xcd = orig & 7, off = orig >> 3;
    return (xcd < r ? xcd * (q + 1) : r * (q + 1) + (xcd - r) * q) + off;
}

// Grid A: [b][gy][gx][z].  Grid B (blurred): [b][gy][z][gx].

// ---- gather splat: 4 threads/cell, ONE packed ds_add_u32 per pixel ----
__global__ __launch_bounds__(256) void splat_gather_kernel(
    const float* __restrict__ img, __half2* __restrict__ grid, int nImg, int imgBase,
    int nBlocks)
{
    __shared__ unsigned lbin[16 * 64];   // [gz][cell], bank = cell%32

    int tid = threadIdx.x;
    int c   = tid & 63;
    int q   = tid >> 6;
    int blk = xcd_swizzle(blockIdx.x, nBlocks);
    int cellIdx = blk * 64 + c;
    int total = nImg * GH * GW;

    for (int i = tid; i < 16 * 64; i += 256) lbin[i] = 0u;
    __syncthreads();

    if (cellIdx < total) {
        int b   = cellIdx / (GH * GW);
        int rem = cellIdx - b * (GH * GW);
        int gy  = rem / GW;
        int gx  = rem - gy * GW;
        const float* ib = img + (size_t)(imgBase + b) * (HDIM * WDIM);

        bool interior = (gx >= 1) & (gx <= 127) & (gy >= 1) & (gy <= 127);
        if (interior) {
            int py = gy & 1, px = gx & 1;
            int ylo = 8 * gy - 4 + py;
            int nr  = 9 - 2 * py;
            int ax  = 8 * gx - 4;
            for (int r = q; r < nr; r += 4) {
                const float* rp = ib + (size_t)(ylo + r) * WDIM + ax;
                float4 A = *(const float4*)rp;
                float4 B = *(const float4*)(rp + 4);
                float  cv = rp[8];
                float e7[7] = {A.y, A.z, A.w, B.x, B.y, B.z, B.w};
                #pragma unroll
                for (int j = 0; j < 7; ++j) {
                    float v = e7[j];
                    int gz = min(max((int)rintf(v * 15.0f), 0), 15);
                    atomicAdd(&lbin[gz * 64 + c], PKONE + (unsigned)rintf(v * PKSCL));
                }
                if (!px) {
                    int gz = min(max((int)rintf(A.x * 15.0f), 0), 15);
                    atomicAdd(&lbin[gz * 64 + c], PKONE + (unsigned)rintf(A.x * PKSCL));
                    gz = min(max((int)rintf(cv * 15.0f), 0), 15);
                    atomicAdd(&lbin[gz * 64 + c], PKONE + (unsigned)rintf(cv * PKSCL));
                }
            }
        } else {
            int ylo = max(0, 8 * gy - 4 + (gy & 1));
            int yhi = min(HDIM - 1, 8 * gy + 4 - (gy & 1));
            int xlo = max(0, 8 * gx - 4 + (gx & 1));
            int xhi = min(WDIM - 1, 8 * gx + 4 - (gx & 1));
            for (int y = ylo + q; y <= yhi; y += 4) {
                const float* row = ib + (size_t)y * WDIM;
                for (int x = xlo; x <= xhi; ++x) {
                    float v = row[x];
                    int gz = min(max((int)rintf(v * 15.0f), 0), 15);
                    atomicAdd(&lbin[gz * 64 + c], PKONE + (unsigned)rintf(v * PKSCL));
                }
            }
        }
    }
    __syncthreads();

    if (cellIdx < total) {
        __half2* dst = grid + (size_t)cellIdx * GZ;
        int zlo = q * 4;
        int zhi = (q == 3) ? 17 : zlo + 4;
        for (int z = zlo; z < zhi; ++z) {
            float vx = 0.f, vy = 0.f;
            if (z != 16) {
                unsigned w = lbin[z * 64 + c];
                vx = (float)(w & PKMASK) * PKINV;
                vy = (float)(w >> 25);
            }
            dst[z] = __floats2half2_rn(vx, vy);
        }
    }
}

// ---- single-pass blur, x-split halves: 2 blocks/row -> 12 blocks/CU ----
// h=0: out gx 0..64,  stage gx 0..66  (67 cols)
// h=1: out gx 65..128, stage gx 63..128 (66 cols)
// LDS 9.1 KB; halo overhead 3%. y-taps fused into staging (unrolled+predicated).
#define NST_MAX (67*GZ)   // 1139
#define NRI2 5            // ceil(1139/256)

__global__ __launch_bounds__(256) void blur_yxz_row(
    const __half2* __restrict__ in, __half2* __restrict__ out,
    const float* __restrict__ kfs, const float* __restrict__ kfr)
{
    __shared__ float2 sbin[NST_MAX];   // 9112 B

    int tid = threadIdx.x;
    int gyh = xcd_swizzle(blockIdx.x, 2 * GH);
    int gy  = gyh >> 1;
    int h   = gyh & 1;
    int b   = blockIdx.y;

    int gxs  = h ? 63 : 0;      // stage base column
    int ncol = h ? 66 : 67;     // staged columns
    int nst  = ncol * GZ;
    int olo  = h ? 2 : 0;       // first out column (local)
    int ocnt = h ? 64 : 65;     // out columns
    int gxo  = h ? 65 : 0;      // first out column (global)

    float ks[5] = {kfs[0], kfs[1], kfs[2], kfs[3], kfs[4]};
    float kr[5] = {kfr[0], kfr[1], kfr[2], kfr[3], kfr[4]};

    // stage columns [gxs, gxs+ncol) of row gy with y-blur applied
    const __half2* gb = in + (size_t)b * CELLS + (size_t)gxs * GZ;
    float2 st[NRI2];
    #pragma unroll
    for (int it = 0; it < NRI2; ++it) {
        int i = tid + it * 256;
        float2 a; a.x = 0.f; a.y = 0.f;
        if (i < nst) {
            #pragma unroll
            for (int t = 0; t < 5; ++t) {
                int yy = gy + t - 2;
                if (yy >= 0 && yy < GH) {
                    float2 g = __half22float2(gb[(size_t)yy * ROWSZ + i]);
                    a.x += ks[t] * g.x;
                    a.y += ks[t] * g.y;
                }
            }
        }
        st[it] = a;
    }
    #pragma unroll
    for (int it = 0; it < NRI2; ++it) {
        int i = tid + it * 256;
        if (i < nst) sbin[i] = st[it];
    }
    __syncthreads();

    // x blur into registers; o = lx*17 + z, taps at o + (t-2)*17, global-predicated
    float2 rt[NRI2];
    #pragma unroll
    for (int it = 0; it < NRI2; ++it) {
        int o = tid + it * 256;
        float2 a; a.x = 0.f; a.y = 0.f;
        if (o < nst) {
            int lx = o / GZ;
            #pragma unroll
            for (int t = 0; t < 5; ++t) {
                int xg = gxs + lx + t - 2;          // global tap column
                int lo = o + (t - 2) * GZ;
                if (xg >= 0 && xg < GW && lo >= 0 && lo < nst) {
                    float2 g = sbin[lo];
                    a.x += ks[t] * g.x;
                    a.y += ks[t] * g.y;
                }
            }
        }
        rt[it] = a;
    }
    __syncthreads();
    #pragma unroll
    for (int it = 0; it < NRI2; ++it) {
        int o = tid + it * 256;
        if (o < nst) sbin[o] = rt[it];   // sbin = yx-blurred [lx][z]
    }
    __syncthreads();

    // z blur + transposed store [gy][z][gx]; o2 = z*ocnt + j
    __half2* ob = out + (size_t)b * CELLS + (size_t)gy * ROWSZ + gxo;
    int nout = ocnt * GZ;
    for (int o2 = tid; o2 < nout; o2 += 256) {
        int z  = o2 / ocnt;
        int j  = o2 - z * ocnt;
        int cb = (olo + j) * GZ;
        float ax = 0.f, ay = 0.f;
        #pragma unroll
        for (int t = 0; t < 5; ++t) {
            int zz = z + t - 2;
            if (zz >= 0 && zz < GZ) {
                float2 g = sbin[cb + zz];
                ax += kr[t] * g.x;
                ay += kr[t] * g.y;
            }
        }
        ob[(size_t)z * GW + j] = __floats2half2_rn(ax, ay);
    }
}

// ---- slice (r12 layout) + XCD swizzle; half2 global, f32 LDS ----
#define XP2   136
#define RST   XP2
#define ZST   (2*XP2)

__global__ __launch_bounds__(256) void slice_rows_kernel(
    const float* __restrict__ img, const __half2* __restrict__ grid,
    float* __restrict__ out, int imgBase)
{
    __shared__ float2 sg[GZ * ZST];   // 36992 B

    int tid = threadIdx.x;
    int k   = xcd_swizzle(blockIdx.x, HDIM / 8);
    int b   = blockIdx.y;

    const __half2* gsrc = grid + (size_t)b * CELLS + (size_t)k * ROWSZ;
    for (int i = tid; i < 2 * ROWSZ; i += 256) {
        int r   = i / ROWSZ;
        int rem = i - r * ROWSZ;
        int z   = rem / GW;
        int x0  = rem - z * GW;
        sg[z * ZST + r * RST + x0] = __half22float2(gsrc[i]);
    }
    __syncthreads();

    int x   = tid << 2;
    int x0v = tid >> 1;
    float txb = (float)(x & 7) * 0.125f;

    size_t rowBase = (size_t)(imgBase + b) * (HDIM * WDIM) + (size_t)(k << 3) * WDIM + x;

    #pragma unroll
    for (int r = 0; r < 8; ++r) {
        size_t pixBase = rowBase + (size_t)r * WDIM;
        float4 v4 = *(const float4*)(img + pixBase);
        float ty = (float)r * 0.125f;
        float wy0 = 1.f - ty, wy1 = ty;

        float vv[4] = {v4.x, v4.y, v4.z, v4.w};
        float rr[4];
        #pragma unroll
        for (int j = 0; j < 4; ++j) {
            float v  = vv[j];
            float fz = fminf(fmaxf(v * 15.0f, 0.0f), 15.0f);
            float zf = floorf(fz);
            int   z0 = (int)zf;
            float tz = fz - zf;
            float tx = txb + (float)j * 0.125f;
            float wx0 = 1.f - tx, wx1 = tx;
            float wz0 = 1.f - tz, wz1 = tz;

            int base = z0 * ZST + x0v;
            float2 g000 = sg[base];
            float2 g010 = sg[base + 1];
            float2 g100 = sg[base + RST];
            float2 g110 = sg[base + RST + 1];
            float2 g001 = sg[base + ZST];
            float2 g011 = sg[base + ZST + 1];
            float2 g101 = sg[base + ZST + RST];
            float2 g111 = sg[base + ZST + RST + 1];

            float ov = 0.f, ow = 0.f, w;
            w = wy0 * wx0 * wz0; ov += w * g000.x; ow += w * g000.y;
            w = wy0 * wx0 * wz1; ov += w * g001.x; ow += w * g001.y;
            w = wy0 * wx1 * wz0; ov += w * g010.x; ow += w * g010.y;
            w = wy0 * wx1 * wz1; ov += w * g011.x; ow += w * g011.y;
            w = wy1 * wx0 * wz0; ov += w * g100.x; ow += w * g100.y;
            w = wy1 * wx0 * wz1; ov += w * g101.x; ow += w * g101.y;
            w = wy1 * wx1 * wz0; ov += w * g110.x; ow += w * g110.y;
            w = wy1 * wx1 * wz1; ov += w * g111.x; ow += w * g111.y;
            rr[j] = ov / (ow + EPSV);
        }
        float4 r4; r4.x = rr[0]; r4.y = rr[1]; r4.z = rr[2]; r4.w = rr[3];
        *(float4*)(out + pixBase) = r4;
    }
}

extern "C" void kernel_launch(void* const* d_in, const int* in_sizes, int n_in,
                              void* d_out, int out_size, void* d_ws, size_t ws_size,
                              hipStream_t stream)
{
    const float* img = (const float*)d_in[0];
    const float* fs  = (const float*)d_in[2];
    const float* fr  = (const float*)d_in[3];
    float* out = (float*)d_out;

    int nImgTotal = in_sizes[0] / (HDIM * WDIM);   // 12
    size_t perImgBytes = (size_t)CELLS * sizeof(__half2);

    int maxChunk = (int)(ws_size / (2 * perImgBytes));
    if (maxChunk < 1) return;
    if (maxChunk > nImgTotal) maxChunk = nImgTotal;

    for (int base = 0; base < nImgTotal; base += maxChunk) {
        int c = nImgTotal - base;
        if (c > maxChunk) c = maxChunk;

        __half2* A = (__half2*)d_ws;
        __half2* B = A + (size_t)c * CELLS;

        int nCells = c * GH * GW;
        int cellBlocks = (nCells + 63) / 64;
        splat_gather_kernel<<<cellBlocks, 256, 0, stream>>>(img, A, c, base, cellBlocks);

        dim3 bgrid(2 * GH, c);                     // 258 x c half-row blocks
        blur_yxz_row<<<bgrid, 256, 0, stream>>>(A, B, fs, fr);

        dim3 sgrid(HDIM / 8, c);
        slice_rows_kernel<<<sgrid, 256, 0, stream>>>(img, B, out, base);
    }
}

// Round 26
// 84.846 us; speedup vs baseline: 1.0210x; 1.0210x over previous
//
#include <hip/hip_runtime.h>
#include <hip/hip_fp16.h>

#define S_SIGMA 8
#define NBINS   16
#define HDIM    1024
#define WDIM    1024
#define GH      129   // (1024-1)/8 + 2
#define GW      129
#define GZ      17    // NBINS + 1
#define CELLS   (GH*GW*GZ)   // 282897 cells per image
#define ROWSZ   (GW*GZ)      // 2193 cells per grid row
#define EPSV    1e-8f
// packed bin: count in bits 25..31 (max 81 < 128), val*4096 in bits 0..24
#define PKONE   (1u << 25)
#define PKMASK  0x1FFFFFFu
#define PKSCL   4096.0f
#define PKINV   (1.0f/4096.0f)

// Grids stored as half2 (val, wt): 4 B/cell — halves all grid traffic.
// All arithmetic and LDS remain f32.

// Bijective XCD swizzle (m204): contiguous work chunk per XCD.
__device__ __forceinline__ int xcd_swizzle(int orig, int nwg) {
    int q = nwg >> 3, r = nwg & 7;
    int xcd = orig & 7, off = orig >> 3;
    return (xcd < r ? xcd * (q + 1) : r * (q + 1) + (xcd - r) * q) + off;
}

// Grid A: [b][gy][gx][z].  Grid B (blurred): [b][gy][z][gx].

// ---- gather splat: 4 threads/cell, ONE packed ds_add_u32 per pixel ----
__global__ __launch_bounds__(256) void splat_gather_kernel(
    const float* __restrict__ img, __half2* __restrict__ grid, int nImg, int imgBase,
    int nBlocks)
{
    __shared__ unsigned lbin[16 * 64];   // [gz][cell], bank = cell%32

    int tid = threadIdx.x;
    int c   = tid & 63;
    int q   = tid >> 6;
    int blk = xcd_swizzle(blockIdx.x, nBlocks);
    int cellIdx = blk * 64 + c;
    int total = nImg * GH * GW;

    for (int i = tid; i < 16 * 64; i += 256) lbin[i] = 0u;
    __syncthreads();

    if (cellIdx < total) {
        int b   = cellIdx / (GH * GW);
        int rem = cellIdx - b * (GH * GW);
        int gy  = rem / GW;
        int gx  = rem - gy * GW;
        const float* ib = img + (size_t)(imgBase + b) * (HDIM * WDIM);

        bool interior = (gx >= 1) & (gx <= 127) & (gy >= 1) & (gy <= 127);
        if (interior) {
            int py = gy & 1, px = gx & 1;
            int ylo = 8 * gy - 4 + py;
            int nr  = 9 - 2 * py;
            int ax  = 8 * gx - 4;
            for (int r = q; r < nr; r += 4) {
                const float* rp = ib + (size_t)(ylo + r) * WDIM + ax;
                float4 A = *(const float4*)rp;
                float4 B = *(const float4*)(rp + 4);
                float  cv = rp[8];
                float e7[7] = {A.y, A.z, A.w, B.x, B.y, B.z, B.w};
                #pragma unroll
                for (int j = 0; j < 7; ++j) {
                    float v = e7[j];
                    int gz = min(max((int)rintf(v * 15.0f), 0), 15);
                    atomicAdd(&lbin[gz * 64 + c], PKONE + (unsigned)rintf(v * PKSCL));
                }
                if (!px) {
                    int gz = min(max((int)rintf(A.x * 15.0f), 0), 15);
                    atomicAdd(&lbin[gz * 64 + c], PKONE + (unsigned)rintf(A.x * PKSCL));
                    gz = min(max((int)rintf(cv * 15.0f), 0), 15);
                    atomicAdd(&lbin[gz * 64 + c], PKONE + (unsigned)rintf(cv * PKSCL));
                }
            }
        } else {
            int ylo = max(0, 8 * gy - 4 + (gy & 1));
            int yhi = min(HDIM - 1, 8 * gy + 4 - (gy & 1));
            int xlo = max(0, 8 * gx - 4 + (gx & 1));
            int xhi = min(WDIM - 1, 8 * gx + 4 - (gx & 1));
            for (int y = ylo + q; y <= yhi; y += 4) {
                const float* row = ib + (size_t)y * WDIM;
                for (int x = xlo; x <= xhi; ++x) {
                    float v = row[x];
                    int gz = min(max((int)rintf(v * 15.0f), 0), 15);
                    atomicAdd(&lbin[gz * 64 + c], PKONE + (unsigned)rintf(v * PKSCL));
                }
            }
        }
    }
    __syncthreads();

    if (cellIdx < total) {
        __half2* dst = grid + (size_t)cellIdx * GZ;
        int zlo = q * 4;
        int zhi = (q == 3) ? 17 : zlo + 4;
        for (int z = zlo; z < zhi; ++z) {
            float vx = 0.f, vy = 0.f;
            if (z != 16) {
                unsigned w = lbin[z * 64 + c];
                vx = (float)(w & PKMASK) * PKINV;
                vy = (float)(w >> 25);
            }
            dst[z] = __floats2half2_rn(vx, vy);
        }
    }
}

// ---- single-pass blur + XCD swizzle; half2 global, f32 LDS ----
#define NRI 9   // ceil(2193/256)

__global__ __launch_bounds__(256) void blur_yxz_row(
    const __half2* __restrict__ in, __half2* __restrict__ out,
    const float* __restrict__ kfs, const float* __restrict__ kfr)
{
    __shared__ float2 sbin[ROWSZ];   // 17544 B

    int tid = threadIdx.x;
    int gy  = xcd_swizzle(blockIdx.x, GH);
    int b   = blockIdx.y;

    float ks[5] = {kfs[0], kfs[1], kfs[2], kfs[3], kfs[4]};
    float kr[5] = {kfr[0], kfr[1], kfr[2], kfr[3], kfr[4]};

    // stage row gy with y-blur; taps unrolled + predicated (parallel loads)
    const __half2* gb = in + (size_t)b * CELLS;
    float2 st[NRI];
    #pragma unroll
    for (int it = 0; it < NRI; ++it) {
        int i = tid + it * 256;
        float2 a; a.x = 0.f; a.y = 0.f;
        if (i < ROWSZ) {
            #pragma unroll
            for (int t = 0; t < 5; ++t) {
                int yy = gy + t - 2;
                if (yy >= 0 && yy < GH) {
                    float2 g = __half22float2(gb[(size_t)yy * ROWSZ + i]);
                    a.x += ks[t] * g.x;
                    a.y += ks[t] * g.y;
                }
            }
        }
        st[it] = a;
    }
    #pragma unroll
    for (int it = 0; it < NRI; ++it) {
        int i = tid + it * 256;
        if (i < ROWSZ) sbin[i] = st[it];
    }
    __syncthreads();

    // x blur into registers; o = gx*17 + z, reads at o + (t-2)*17
    float2 rt[NRI];
    #pragma unroll
    for (int it = 0; it < NRI; ++it) {
        int o = tid + it * 256;
        float2 a; a.x = 0.f; a.y = 0.f;
        if (o < ROWSZ) {
            int gx = o / GZ;
            #pragma unroll
            for (int t = 0; t < 5; ++t) {
                int xx = gx + t - 2;
                if (xx >= 0 && xx < GW) {
                    float2 g = sbin[o + (t - 2) * GZ];
                    a.x += ks[t] * g.x;
                    a.y += ks[t] * g.y;
                }
            }
        }
        rt[it] = a;
    }
    __syncthreads();
    #pragma unroll
    for (int it = 0; it < NRI; ++it) {
        int o = tid + it * 256;
        if (o < ROWSZ) sbin[o] = rt[it];   // sbin = yx-blurred [gx][z]
    }
    __syncthreads();

    // z blur + transposed store [gy][z][gx]; coalesced half2 row writes
    __half2* ob = out + (size_t)b * CELLS + (size_t)gy * ROWSZ;
    for (int o2 = tid; o2 < ROWSZ; o2 += 256) {
        int z  = o2 / GW;
        int gx = o2 - z * GW;
        float ax = 0.f, ay = 0.f;
        #pragma unroll
        for (int t = 0; t < 5; ++t) {
            int zz = z + t - 2;
            if (zz >= 0 && zz < GZ) {
                float2 g = sbin[gx * GZ + zz];
                ax += kr[t] * g.x;
                ay += kr[t] * g.y;
            }
        }
        ob[o2] = __floats2half2_rn(ax, ay);
    }
}

// ---- slice (r12 layout) + XCD swizzle; half2 global, f32 LDS ----
#define XP2   136
#define RST   XP2
#define ZST   (2*XP2)

__global__ __launch_bounds__(256) void slice_rows_kernel(
    const float* __restrict__ img, const __half2* __restrict__ grid,
    float* __restrict__ out, int imgBase)
{
    __shared__ float2 sg[GZ * ZST];   // 36992 B

    int tid = threadIdx.x;
    int k   = xcd_swizzle(blockIdx.x, HDIM / 8);
    int b   = blockIdx.y;

    const __half2* gsrc = grid + (size_t)b * CELLS + (size_t)k * ROWSZ;
    for (int i = tid; i < 2 * ROWSZ; i += 256) {
        int r   = i / ROWSZ;
        int rem = i - r * ROWSZ;
        int z   = rem / GW;
        int x0  = rem - z * GW;
        sg[z * ZST + r * RST + x0] = __half22float2(gsrc[i]);
    }
    __syncthreads();

    int x   = tid << 2;
    int x0v = tid >> 1;
    float txb = (float)(x & 7) * 0.125f;

    size_t rowBase = (size_t)(imgBase + b) * (HDIM * WDIM) + (size_t)(k << 3) * WDIM + x;

    #pragma unroll
    for (int r = 0; r < 8; ++r) {
        size_t pixBase = rowBase + (size_t)r * WDIM;
        float4 v4 = *(const float4*)(img + pixBase);
        float ty = (float)r * 0.125f;
        float wy0 = 1.f - ty, wy1 = ty;

        float vv[4] = {v4.x, v4.y, v4.z, v4.w};
        float rr[4];
        #pragma unroll
        for (int j = 0; j < 4; ++j) {
            float v  = vv[j];
            float fz = fminf(fmaxf(v * 15.0f, 0.0f), 15.0f);
            float zf = floorf(fz);
            int   z0 = (int)zf;
            float tz = fz - zf;
            float tx = txb + (float)j * 0.125f;
            float wx0 = 1.f - tx, wx1 = tx;
            float wz0 = 1.f - tz, wz1 = tz;

            int base = z0 * ZST + x0v;
            float2 g000 = sg[base];
            float2 g010 = sg[base + 1];
            float2 g100 = sg[base + RST];
            float2 g110 = sg[base + RST + 1];
            float2 g001 = sg[base + ZST];
            float2 g011 = sg[base + ZST + 1];
            float2 g101 = sg[base + ZST + RST];
            float2 g111 = sg[base + ZST + RST + 1];

            float ov = 0.f, ow = 0.f, w;
            w = wy0 * wx0 * wz0; ov += w * g000.x; ow += w * g000.y;
            w = wy0 * wx0 * wz1; ov += w * g001.x; ow += w * g001.y;
            w = wy0 * wx1 * wz0; ov += w * g010.x; ow += w * g010.y;
            w = wy0 * wx1 * wz1; ov += w * g011.x; ow += w * g011.y;
            w = wy1 * wx0 * wz0; ov += w * g100.x; ow += w * g100.y;
            w = wy1 * wx0 * wz1; ov += w * g101.x; ow += w * g101.y;
            w = wy1 * wx1 * wz0; ov += w * g110.x; ow += w * g110.y;
            w = wy1 * wx1 * wz1; ov += w * g111.x; ow += w * g111.y;
            rr[j] = ov / (ow + EPSV);
        }
        float4 r4; r4.x = rr[0]; r4.y = rr[1]; r4.z = rr[2]; r4.w = rr[3];
        *(float4*)(out + pixBase) = r4;
    }
}

extern "C" void kernel_launch(void* const* d_in, const int* in_sizes, int n_in,
                              void* d_out, int out_size, void* d_ws, size_t ws_size,
                              hipStream_t stream)
{
    const float* img = (const float*)d_in[0];
    const float* fs  = (const float*)d_in[2];
    const float* fr  = (const float*)d_in[3];
    float* out = (float*)d_out;

    int nImgTotal = in_sizes[0] / (HDIM * WDIM);   // 12
    size_t perImgBytes = (size_t)CELLS * sizeof(__half2);   // 1.13 MB

    int maxChunk = (int)(ws_size / (2 * perImgBytes));
    if (maxChunk < 1) return;
    if (maxChunk > nImgTotal) maxChunk = nImgTotal;

    for (int base = 0; base < nImgTotal; base += maxChunk) {
        int c = nImgTotal - base;
        if (c > maxChunk) c = maxChunk;

        __half2* A = (__half2*)d_ws;
        __half2* B = A + (size_t)c * CELLS;

        int nCells = c * GH * GW;
        int cellBlocks = (nCells + 63) / 64;
        splat_gather_kernel<<<cellBlocks, 256, 0, stream>>>(img, A, c, base, cellBlocks);

        dim3 bgrid(GH, c);
        blur_yxz_row<<<bgrid, 256, 0, stream>>>(A, B, fs, fr);

        dim3 sgrid(HDIM / 8, c);
        slice_rows_kernel<<<sgrid, 256, 0, stream>>>(img, B, out, base);
    }
}